// Round 1
// baseline (200.084 us; speedup 1.0000x reference)
//
#include <hip/hip_runtime.h>
#include <stdint.h>

// DataEmbedder: fused categorical embedding gather + numeric passthrough concat.
// dataset [R=262144, 12] fp32: cols 0-3 = raw category ids (as floats),
// cols 4-11 = numeric features. Output [R, 128] fp32:
//   [emb0(32) | emb1(64) | emb2(16) | emb3(8) | numeric(8)]
// LUTs are identity permutations but applied anyway (cheap, L2-resident).
//
// One thread per 16B output chunk: 32 chunks/row, k = tid & 31.
//   k in [0,8)   -> emb0[id0][k*4 .. +4)
//   k in [8,24)  -> emb1[id1][(k-8)*4 ..)
//   k in [24,28) -> emb2[id2][(k-24)*4 ..)
//   k in [28,30) -> emb3[id3][(k-28)*4 ..)
//   k in [30,32) -> dataset[row][4 + (k-30)*4 ..)   (48*row+16 bytes: 16B aligned)
// Stores: wave64 covers 2 rows = 1KB contiguous -> fully coalesced.

__global__ __launch_bounds__(256) void data_embedder_kernel(
    const float* __restrict__ ds,
    const float* __restrict__ e0, const int* __restrict__ l0,
    const float* __restrict__ e1, const int* __restrict__ l1,
    const float* __restrict__ e2, const int* __restrict__ l2,
    const float* __restrict__ e3, const int* __restrict__ l3,
    float* __restrict__ out, int nrows)
{
    int tid = blockIdx.x * blockDim.x + threadIdx.x;
    int row = tid >> 5;
    int k   = tid & 31;
    if (row >= nrows) return;

    const float* drow = ds + (size_t)row * 12;
    float4 v;
    if (k < 8) {
        int id = l0[(int)drow[0]];
        v = *(const float4*)(e0 + (size_t)id * 32 + k * 4);
    } else if (k < 24) {
        int id = l1[(int)drow[1]];
        v = *(const float4*)(e1 + (size_t)id * 64 + (k - 8) * 4);
    } else if (k < 28) {
        int id = l2[(int)drow[2]];
        v = *(const float4*)(e2 + (size_t)id * 16 + (k - 24) * 4);
    } else if (k < 30) {
        int id = l3[(int)drow[3]];
        v = *(const float4*)(e3 + (size_t)id * 8 + (k - 28) * 4);
    } else {
        v = *(const float4*)(drow + 4 + (k - 30) * 4);
    }
    *(float4*)(out + (size_t)row * 128 + k * 4) = v;
}

extern "C" void kernel_launch(void* const* d_in, const int* in_sizes, int n_in,
                              void* d_out, int out_size, void* d_ws, size_t ws_size,
                              hipStream_t stream) {
    // setup_inputs() dict order: dataset, emb0, lut0, emb1, lut1, emb2, lut2, emb3, lut3
    const float* ds = (const float*)d_in[0];
    const float* e0 = (const float*)d_in[1];
    const int*   l0 = (const int*)  d_in[2];
    const float* e1 = (const float*)d_in[3];
    const int*   l1 = (const int*)  d_in[4];
    const float* e2 = (const float*)d_in[5];
    const int*   l2 = (const int*)  d_in[6];
    const float* e3 = (const float*)d_in[7];
    const int*   l3 = (const int*)  d_in[8];
    float* out = (float*)d_out;

    int nrows = in_sizes[0] / 12;           // 64 * 4096 = 262144
    long total = (long)nrows * 32;          // one thread per float4 chunk
    int block = 256;
    int grid = (int)((total + block - 1) / block);

    data_embedder_kernel<<<grid, block, 0, stream>>>(
        ds, e0, l0, e1, l1, e2, l2, e3, l3, out, nrows);
}

// Round 4
// 176.172 us; speedup vs baseline: 1.1357x; 1.1357x over previous
//
#include <hip/hip_runtime.h>
#include <stdint.h>

// DataEmbedder: fused categorical embedding gather + numeric passthrough concat.
// dataset [R=262144, 12] fp32: cols 0-3 = raw category ids (as floats),
// cols 4-11 = numeric features. Output [R, 128] fp32:
//   [emb0(32) | emb1(64) | emb2(16) | emb3(8) | numeric(8)]
//
// R4: R3's branchless structure with NORMAL (coherent, through-L2) stores.
// NT stores (R3) were ~22us faster but lost updates: the harness poisons
// d_out through the cached path, and dirty 0xAA lines in L2 evict AFTER the
// kernel's L2-bypassing nt writes, clobbering them (post-timing absmax 3.53).
// Coherent stores write-hit those lines in L2 -> always correct.
//
// One thread per 16B output chunk (k = tid & 31). Every lane runs the SAME
// instruction sequence: descriptor via cndmask chains, then 1 dataset dword +
// 1 LUT dword + 1 float4 gather + 1 float4 store. Numeric lanes (k>=30)
// fold in as "table" = ds+4, stride 12, id = row; their LUT read is a safe
// dummy (l3[(int)drow[3]], raw < 50).

typedef float f4 __attribute__((ext_vector_type(4)));

__global__ __launch_bounds__(256) void data_embedder_kernel(
    const float* __restrict__ ds,
    const float* __restrict__ e0, const int* __restrict__ l0,
    const float* __restrict__ e1, const int* __restrict__ l1,
    const float* __restrict__ e2, const int* __restrict__ l2,
    const float* __restrict__ e3, const int* __restrict__ l3,
    float* __restrict__ out, int nrows)
{
    int tid = blockIdx.x * blockDim.x + threadIdx.x;
    int row = tid >> 5;
    int k   = tid & 31;
    if (row >= nrows) return;

    const float* drow = ds + (size_t)row * 12;

    // Per-k segment descriptor, all selects (no divergent branches):
    //   k in [0,8)   emb0: stride 32, col 0
    //   k in [8,24)  emb1: stride 64, col 1
    //   k in [24,28) emb2: stride 16, col 2
    //   k in [28,30) emb3: stride  8, col 3
    //   k in [30,32) numeric: base ds+4, stride 12, id = row
    bool s0 = k < 8, s1 = k < 24, s2 = k < 28, s3 = k < 30;
    const float* base = s0 ? e0 : s1 ? e1 : s2 ? e2 : s3 ? e3 : (ds + 4);
    const int*   lut  = s0 ? l0 : s1 ? l1 : s2 ? l2 : l3;   // k>=30: dummy (safe)
    int stride = s0 ? 32 : s1 ? 64 : s2 ? 16 : s3 ? 8 : 12;
    int off    = (s0 ? k : s1 ? (k - 8) : s2 ? (k - 24) : s3 ? (k - 28) : (k - 30)) * 4;
    int col    = s0 ? 0 : s1 ? 1 : s2 ? 2 : 3;              // k>=30 reads col3 (dummy)

    int raw    = (int)drow[col];          // broadcast within each lane group
    int mapped = lut[raw];                // L2-resident identity permutation
    int id     = s3 ? mapped : row;       // numeric lanes index the dataset by row

    const f4* src = (const f4*)(base + (size_t)id * stride + off);
    f4 v = *src;

    *(f4*)(out + (size_t)row * 128 + k * 4) = v;   // coherent store (through L2)
}

extern "C" void kernel_launch(void* const* d_in, const int* in_sizes, int n_in,
                              void* d_out, int out_size, void* d_ws, size_t ws_size,
                              hipStream_t stream) {
    // setup_inputs() dict order: dataset, emb0, lut0, emb1, lut1, emb2, lut2, emb3, lut3
    const float* ds = (const float*)d_in[0];
    const float* e0 = (const float*)d_in[1];
    const int*   l0 = (const int*)  d_in[2];
    const float* e1 = (const float*)d_in[3];
    const int*   l1 = (const int*)  d_in[4];
    const float* e2 = (const float*)d_in[5];
    const int*   l2 = (const int*)  d_in[6];
    const float* e3 = (const float*)d_in[7];
    const int*   l3 = (const int*)  d_in[8];
    float* out = (float*)d_out;

    int nrows = in_sizes[0] / 12;           // 64 * 4096 = 262144
    long total = (long)nrows * 32;          // one thread per float4 chunk
    int block = 256;
    int grid = (int)((total + block - 1) / block);

    data_embedder_kernel<<<grid, block, 0, stream>>>(
        ds, e0, l0, e1, l1, e2, l2, e3, l3, out, nrows);
}

// Round 5
// 175.553 us; speedup vs baseline: 1.1397x; 1.0035x over previous
//
#include <hip/hip_runtime.h>
#include <stdint.h>

// DataEmbedder: fused categorical embedding gather + numeric passthrough concat.
// dataset [R=262144, 12] fp32: cols 0-3 = raw category ids (as floats),
// cols 4-11 = numeric features. Output [R, 128] fp32:
//   [emb0(32) | emb1(64) | emb2(16) | emb3(8) | numeric(8)]
//
// R5: 2 rows per thread, shared segment descriptor.
// k = tid & 31 picks the 16B output chunk within a row; the descriptor
// (base/lut/stride/off/col) depends ONLY on k, so one thread serving rows
// {2p, 2p+1} computes it once and runs two independent load chains
// (2 id loads + 2 LUT loads + 2 gathers + 2 stores) -> 2x per-thread MLP,
// half the cndmask/address VALU per output byte. Coherent stores (NT loses
// races with the harness's cached d_out re-poison -- R3 post-mortem).
//
// Store coalescing: store#0 lanes 0-31 -> row 2p chunks 0-31 (512B run),
// lanes 32-63 -> row 2p+2 (512B run at +1KB); all full 64B lines.

typedef float f4 __attribute__((ext_vector_type(4)));

__global__ __launch_bounds__(256) void data_embedder_kernel(
    const float* __restrict__ ds,
    const float* __restrict__ e0, const int* __restrict__ l0,
    const float* __restrict__ e1, const int* __restrict__ l1,
    const float* __restrict__ e2, const int* __restrict__ l2,
    const float* __restrict__ e3, const int* __restrict__ l3,
    float* __restrict__ out, int nrows)
{
    int tid  = blockIdx.x * blockDim.x + threadIdx.x;
    int pair = tid >> 5;
    int k    = tid & 31;
    if (pair >= (nrows >> 1)) return;
    int row0 = pair << 1;

    // Segment descriptor, function of k only (shared across both rows):
    //   k in [0,8)   emb0: stride 32, col 0
    //   k in [8,24)  emb1: stride 64, col 1
    //   k in [24,28) emb2: stride 16, col 2
    //   k in [28,30) emb3: stride  8, col 3
    //   k in [30,32) numeric: base ds+4, stride 12, id = row
    bool s0 = k < 8, s1 = k < 24, s2 = k < 28, s3 = k < 30;
    const float* base = s0 ? e0 : s1 ? e1 : s2 ? e2 : s3 ? e3 : (ds + 4);
    const int*   lut  = s0 ? l0 : s1 ? l1 : s2 ? l2 : l3;   // k>=30: dummy (safe, raw<50)
    int stride = s0 ? 32 : s1 ? 64 : s2 ? 16 : s3 ? 8 : 12;
    int off    = (s0 ? k : s1 ? (k - 8) : s2 ? (k - 24) : s3 ? (k - 28) : (k - 30)) * 4;
    int col    = s0 ? 0 : s1 ? 1 : s2 ? 2 : 3;              // k>=30 reads col3 (dummy)

    const float* drow0 = ds + (size_t)row0 * 12;

    // Two independent chains (issued back-to-back for MLP):
    int raw0 = (int)drow0[col];
    int raw1 = (int)drow0[12 + col];
    int m0 = lut[raw0];
    int m1 = lut[raw1];
    int id0 = s3 ? m0 : row0;
    int id1 = s3 ? m1 : row0 + 1;

    f4 v0 = *(const f4*)(base + (size_t)id0 * stride + off);
    f4 v1 = *(const f4*)(base + (size_t)id1 * stride + off);

    float* orow = out + (size_t)row0 * 128 + k * 4;
    *(f4*)(orow)       = v0;
    *(f4*)(orow + 128) = v1;
}

extern "C" void kernel_launch(void* const* d_in, const int* in_sizes, int n_in,
                              void* d_out, int out_size, void* d_ws, size_t ws_size,
                              hipStream_t stream) {
    // setup_inputs() dict order: dataset, emb0, lut0, emb1, lut1, emb2, lut2, emb3, lut3
    const float* ds = (const float*)d_in[0];
    const float* e0 = (const float*)d_in[1];
    const int*   l0 = (const int*)  d_in[2];
    const float* e1 = (const float*)d_in[3];
    const int*   l1 = (const int*)  d_in[4];
    const float* e2 = (const float*)d_in[5];
    const int*   l2 = (const int*)  d_in[6];
    const float* e3 = (const float*)d_in[7];
    const int*   l3 = (const int*)  d_in[8];
    float* out = (float*)d_out;

    int nrows = in_sizes[0] / 12;                 // 64 * 4096 = 262144 (even)
    long total = (long)(nrows / 2) * 32;          // one thread per 2 chunks
    int block = 256;
    int grid = (int)((total + block - 1) / block);

    data_embedder_kernel<<<grid, block, 0, stream>>>(
        ds, e0, l0, e1, l1, e2, l2, e3, l3, out, nrows);
}